// Round 12
// baseline (175.077 us; speedup 1.0000x reference)
//
#include <hip/hip_runtime.h>

// Flow1: RealNVP coupling flow. K=32 B=4096 ZS=128 ZH=64 HS=50 NF=2.
// Round 16: s_setprio around MFMA clusters (T5). Ledger of falsified stall
// theories, all measured: occupancy shape (r8), ILP/wave-count (r11), LDS
// round-trips (r12), trans pipe (r13), VALU issue volume (r14: busy 32->28us,
// duration unchanged), weight scatter (r15). Duration pinned 70-73us; no pipe
// saturated (VALU 27us, MFMA 5us, HBM floor 17us vs 70 total). Residual =
// scheduler-level: independent waves all sitting in the same phase mix.
// T5's measured analog: +4-7% on independent-wave attn (m191); null only on
// barrier-lockstep GEMM (m190). Our kernel = zero barriers, independent
// waves -> the applicable regime. setprio(1) wraps each MFMA cluster so the
// CU scheduler favors matrix-feeding waves during arbitration.
// Pre-commit: |delta|<3% => declare source-level floor next round.
//
// Layouts (m89/m91-verified):
//   A-frag: A[m][k], m=lane&15, k=quad*8+j (j=0..7) per 32-K-tile
//   B-frag: B[k][n], n=lane&15, k=quad*8+j
//   C/D   : D[m][n], n=lane&15, m=quad*4+reg

typedef unsigned short ushort_t;
typedef unsigned int   uint_t;
typedef short bf8 __attribute__((ext_vector_type(8)));
typedef float f4  __attribute__((ext_vector_type(4)));
typedef float f2  __attribute__((ext_vector_type(2)));

#define KK   32
#define BB   4096
#define ZSD  128
#define ZHD  64
#define HSD  50
#define NROWS (KK*BB)

// fragment-major weights: per matrix 4nt x 2kt x 64lane x 8shorts = 4096
#define MATS2 4096
#define WGL_SHORTS (12*MATS2)     // 49152 shorts = 98304 B
#define WS_BYTES   (WGL_SHORTS*2 + 768*4)

// hardware bf16 convert (RNE on gfx950)
__device__ __forceinline__ ushort_t f2bf(float f){
  union{__bf16 h; ushort_t u;} v; v.h = (__bf16)f; return v.u;
}

__device__ __forceinline__ float rcp_fast(float x){ return __builtin_amdgcn_rcpf(x); }

// packed 2xf32 fma (VOP3P, 64-bit VGPR pairs)
__device__ __forceinline__ f2 pk_fma(f2 a, f2 b, f2 c){
  f2 d;
  asm("v_pk_fma_f32 %0, %1, %2, %3" : "=v"(d) : "v"(a), "v"(b), "v"(c));
  return d;
}

struct PadeC {
  f2 c21, c1260, c10395, c210, c4725, chalf;
};

// Pade[5/6] tanh on a pair; clamp to +-5 done scalar per element.
__device__ __forceinline__ f2 tanh_pade2(f2 x, const PadeC& C){
  x.x = fminf(fmaxf(x.x, -5.0f), 5.0f);
  x.y = fminf(fmaxf(x.y, -5.0f), 5.0f);
  f2 u  = x*x;
  f2 p  = pk_fma(u, pk_fma(u, C.c21, C.c1260), C.c10395);
  f2 q  = pk_fma(u, pk_fma(u, u + C.c210, C.c4725), C.c10395);
  f2 xp = x*p;
  f2 r; r.x = xp.x*rcp_fast(q.x); r.y = xp.y*rcp_fast(q.y);
  return r;
}

// sigmoid(x) = 0.5 + 0.5*tanh(x/2); |x|<=7.21 by construction -> no clamp.
__device__ __forceinline__ f2 sigmoid_pade2(f2 x, const PadeC& C){
  f2 y  = 0.5f*x;
  f2 u  = y*y;
  f2 p  = pk_fma(u, pk_fma(u, C.c21, C.c1260), C.c10395);
  f2 q  = pk_fma(u, pk_fma(u, u + C.c210, C.c4725), C.c10395);
  f2 yp = y*p;
  f2 t; t.x = yp.x*rcp_fast(q.x); t.y = yp.y*rcp_fast(q.y);
  return pk_fma(t, C.chalf, C.chalf);
}

__device__ __forceinline__ f4 MFMA(bf8 a, bf8 b, f4 c){
  return __builtin_amdgcn_mfma_f32_16x16x32_bf16(a, b, c, 0, 0, 0);
}

// ---- weight preconversion: fp32 -> fragment-major bf16 + fp32 biases.
// t -> (mat, nt, kt, lane, j); value = stored[n=nt*16+(lane&15)]
//                                        [k=kt*32+(lane>>4)*8+j]
// stored0 = W0[h=n][z=k]; stored1/2 = W1/W2[z=n][h=k].
__global__ void convert_weights(const float* __restrict__ W0g,
                                const float* __restrict__ b0g,
                                const float* __restrict__ W1g,
                                const float* __restrict__ b1g,
                                const float* __restrict__ W2g,
                                const float* __restrict__ b2g,
                                ushort_t* __restrict__ wgl)
{
  int t = blockIdx.x*256 + threadIdx.x;
  if (t < WGL_SHORTS){
    int mi   = t / MATS2;            // step*3 + which
    int rem  = t % MATS2;
    int nt   = rem / 1024;
    int rem2 = rem % 1024;
    int kt   = rem2 / 512;
    int rem3 = rem2 % 512;
    int lane = rem3 / 8;
    int j    = rem3 % 8;
    int l15  = lane & 15;
    int quad = lane >> 4;
    int n    = nt*16 + l15;
    int k    = kt*32 + quad*8 + j;
    int step  = mi / 3;
    int which = mi % 3;
    float v = 0.0f;
    if (which == 0){                           // W0[h=n][z=k], k<64 always
      if (n < HSD)  v = W0g[(step*HSD + n)*ZHD + k];
    } else if (which == 1){                    // W1[z=n][h=k]
      if (k < HSD)  v = W1g[(step*ZHD + n)*HSD + k];
    } else {                                   // W2[z=n][h=k]
      if (k < HSD)  v = W2g[(step*ZHD + n)*HSD + k];
    }
    wgl[t] = f2bf(v);
  }
  if (t < 768){                                // biases fp32 padded to 64
    float* bp = (float*)(wgl + WGL_SHORTS);
    int step  = t / 192;
    int rem   = t % 192;
    int which = rem / 64;
    int n     = rem % 64;
    float v = 0.0f;
    if (which == 0){ if (n < HSD) v = b0g[step*HSD + n]; }
    else if (which == 1) v = b1g[step*ZHD + n];
    else                 v = b2g[step*ZHD + n];
    bp[t] = v;
  }
}

// one coupling step; pz = passive-half registers (updated), active already in zAw
__device__ __forceinline__ void do_step(
    int s, float (&pz)[2][16], float (&T)[2][4],
    ushort_t* zAw, ushort_t* hAw,
    const ushort_t* wgl, const float* wsb,
    const PadeC& C,
    int quad, int l15, int lofs, int wr)
{
  // this step's 3 matrices, fragment-major (all loads coalesced 1024B/wave)
  const ushort_t* ws = wgl + (size_t)s*3*MATS2;

  #define WST 72   // LDS activation tile k-stride (shorts), unchanged

  // ---- phase A: H = tanh(Zact @ B0 + b0) ----
  bf8 zf[2][2];
  #pragma unroll
  for (int m=0;m<2;++m)
    #pragma unroll
    for (int kt=0;kt<2;++kt)
      zf[m][kt] = *(const bf8*)(zAw + (m*16 + l15)*WST + kt*32 + quad*8);

  #pragma unroll
  for (int nt=0;nt<4;++nt){
    const ushort_t* wb = ws + nt*1024 + lofs;          // mat0, kt=0 / kt=1
    bf8 w0a = *(const bf8*)(wb);
    bf8 w0b = *(const bf8*)(wb + 512);
    float b0v = wsb[(s*3+0)*64 + nt*16 + l15];
    f2 b0p; b0p.x = b0v; b0p.y = b0v;
    #pragma unroll
    for (int m=0;m<2;++m){
      f4 acc = {0.f,0.f,0.f,0.f};
      __builtin_amdgcn_s_setprio(1);
      acc = MFMA(zf[m][0], w0a, acc);
      acc = MFMA(zf[m][1], w0b, acc);
      __builtin_amdgcn_s_setprio(0);
      f2 a01; a01.x = acc[0]; a01.y = acc[1];
      f2 a23; a23.x = acc[2]; a23.y = acc[3];
      f2 h01 = tanh_pade2(a01 + b0p, C);
      f2 h23 = tanh_pade2(a23 + b0p, C);
      hAw[(m*16 + quad*4 + 0)*WST + nt*16 + l15] = f2bf(h01.x);
      hAw[(m*16 + quad*4 + 1)*WST + nt*16 + l15] = f2bf(h01.y);
      hAw[(m*16 + quad*4 + 2)*WST + nt*16 + l15] = f2bf(h23.x);
      hAw[(m*16 + quad*4 + 3)*WST + nt*16 + l15] = f2bf(h23.y);
    }
  }

  // ---- phase B: MEW = H@B1 + b1 ; SIG = sigmoid(H@B2 + b2) ----
  bf8 hf[2][2];
  #pragma unroll
  for (int m=0;m<2;++m)
    #pragma unroll
    for (int kt=0;kt<2;++kt)
      hf[m][kt] = *(const bf8*)(hAw + (m*16 + l15)*WST + kt*32 + quad*8);

  // product-of-sigmoids accumulators: one log per (m,i) per step
  float sp[2][4];
  #pragma unroll
  for (int m=0;m<2;++m)
    #pragma unroll
    for (int i=0;i<4;++i) sp[m][i] = 1.0f;

  #pragma unroll
  for (int nt=0;nt<4;++nt){
    const ushort_t* w1p = ws + 4096 + nt*1024 + lofs;  // mat1
    const ushort_t* w2p = ws + 8192 + nt*1024 + lofs;  // mat2
    bf8 w1a = *(const bf8*)(w1p);
    bf8 w1b = *(const bf8*)(w1p + 512);
    bf8 w2a = *(const bf8*)(w2p);
    bf8 w2b = *(const bf8*)(w2p + 512);
    float b1v = wsb[(s*3+1)*64 + nt*16 + l15];
    float b2v = wsb[(s*3+2)*64 + nt*16 + l15];
    f2 b2p; b2p.x = b2v; b2p.y = b2v;
    #pragma unroll
    for (int m=0;m<2;++m){
      f4 am = {0.f,0.f,0.f,0.f};
      f4 as = {0.f,0.f,0.f,0.f};
      __builtin_amdgcn_s_setprio(1);
      am = MFMA(hf[m][0], w1a, am);
      am = MFMA(hf[m][1], w1b, am);
      as = MFMA(hf[m][0], w2a, as);
      as = MFMA(hf[m][1], w2b, as);
      __builtin_amdgcn_s_setprio(0);
      f2 s01 = sigmoid_pade2((f2){as[0], as[1]} + b2p, C);
      f2 s23 = sigmoid_pade2((f2){as[2], as[3]} + b2p, C);
      float sg[4] = {s01.x, s01.y, s23.x, s23.y};
      #pragma unroll
      for (int i=0;i<4;++i){
        float mew  = am[i] + b1v;
        sp[m][i] *= sg[i];
        pz[m][nt*4+i] = fmaf(pz[m][nt*4+i], sg[i], mew);
      }
    }
  }

  // 4-term products >= (7.5e-4)^4 ~ 3e-13: safely above fp32 underflow
  #pragma unroll
  for (int m=0;m<2;++m)
    #pragma unroll
    for (int i=0;i<4;++i)
      T[m][i] += __logf(sp[m][i]);

  // new active = just-updated passive -> zA (bf16, A-layout)
  if (wr){
    #pragma unroll
    for (int m=0;m<2;++m)
      #pragma unroll
      for (int nt=0;nt<4;++nt)
        #pragma unroll
        for (int i=0;i<4;++i)
          zAw[(m*16 + quad*4 + i)*WST + nt*16 + l15] = f2bf(pz[m][nt*4+i]);
  }
}

__global__ __launch_bounds__(128) void flow_mfma(
    const float* __restrict__ mean, const float* __restrict__ logvar,
    const float* __restrict__ eps,
    const ushort_t* __restrict__ wgl,
    float* __restrict__ out)
{
  __shared__ __align__(16) ushort_t zA[2][32*WST];      // 2 x 4608 B
  __shared__ __align__(16) ushort_t hA[2][32*WST];      // 2 x 4608 B

  const int tid  = threadIdx.x;
  const int wave = tid >> 6;
  const int lane = tid & 63;
  const int quad = lane >> 4;
  const int l15  = lane & 15;
  const int lofs = lane*8;
  const int rbase = blockIdx.x*64 + wave*32;

  const float* wsb = (const float*)(wgl + WGL_SHORTS);
  ushort_t* zAw = zA[wave];
  ushort_t* hAw = hA[wave];

  PadeC C;
  C.c21    = (f2){21.0f, 21.0f};
  C.c1260  = (f2){1260.0f, 1260.0f};
  C.c10395 = (f2){10395.0f, 10395.0f};
  C.c210   = (f2){210.0f, 210.0f};
  C.c4725  = (f2){4725.0f, 4725.0f};
  C.chalf  = (f2){0.5f, 0.5f};

  // z1D/z2D in C/D layout: [mtile][nt*4+reg] -> row=mtile*16+quad*4+reg,
  // col(z-index within half)=nt*16+l15
  float z1D[2][16], z2D[2][16];
  float T[2][4];                     // T = 0.5*sum(lv+eps^2) + sum(lsig)

  // ---- init: z = eps*exp(0.5*lv)+mean, loaded directly in D-layout ----
  #pragma unroll
  for (int m=0;m<2;++m){
    #pragma unroll
    for (int i=0;i<4;++i){
      int rrow = rbase + m*16 + quad*4 + i;
      int brow = rrow & (BB-1);
      const float* er = eps    + (size_t)rrow*ZSD;
      const float* mr = mean   + (size_t)brow*ZSD;
      const float* vr = logvar + (size_t)brow*ZSD;
      float acc = 0.f;
      #pragma unroll
      for (int nt=0;nt<4;++nt){
        int c1 = nt*16 + l15;
        int c2 = 64 + c1;
        float e1 = er[c1], v1 = vr[c1], m1 = mr[c1];
        float e2 = er[c2], v2 = vr[c2], m2 = mr[c2];
        z1D[m][nt*4+i] = fmaf(e1, __expf(0.5f*v1), m1);
        z2D[m][nt*4+i] = fmaf(e2, __expf(0.5f*v2), m2);
        acc += (v1 + e1*e1) + (v2 + e2*e2);
      }
      T[m][i] = 0.5f*acc;
    }
  }

  // initial active = z1 -> zA
  #pragma unroll
  for (int m=0;m<2;++m)
    #pragma unroll
    for (int nt=0;nt<4;++nt)
      #pragma unroll
      for (int i=0;i<4;++i)
        zAw[(m*16 + quad*4 + i)*WST + nt*16 + l15] = f2bf(z1D[m][nt*4+i]);

  // ---- 4 coupling steps (2 bodies in a non-unrolled loop to bound I$) ----
  #pragma unroll 1
  for (int it=0; it<2; ++it){
    do_step(2*it+0, z2D, T, zAw, hAw, wgl, wsb, C, quad, l15, lofs, 1);
    do_step(2*it+1, z1D, T, zAw, hAw, wgl, wsb, C, quad, l15, lofs, it==0);
  }

  // ---- store z_out (fp32) ----
  #pragma unroll
  for (int m=0;m<2;++m){
    #pragma unroll
    for (int i=0;i<4;++i){
      int rrow = rbase + m*16 + quad*4 + i;
      float* orow = out + (size_t)rrow*ZSD;
      #pragma unroll
      for (int nt=0;nt<4;++nt){
        orow[nt*16 + l15]      = z1D[m][nt*4+i];
        orow[64 + nt*16 + l15] = z2D[m][nt*4+i];
      }
    }
  }

  // ---- logpz = -0.5*128*ln(2pi) - T_rowsum ; reduce T across the 16 lanes
  // of each quad (they cover all 128 cols of rows quad*4+reg) ----
  #pragma unroll
  for (int m=0;m<2;++m)
    #pragma unroll
    for (int i=0;i<4;++i){
      float v = T[m][i];
      v += __shfl_xor(v, 1, 64);
      v += __shfl_xor(v, 2, 64);
      v += __shfl_xor(v, 4, 64);
      v += __shfl_xor(v, 8, 64);
      T[m][i] = v;
    }
  if (l15 == 0){
    const float NC = -0.5f * 128.0f * 1.8378770664093453f;
    #pragma unroll
    for (int m=0;m<2;++m)
      #pragma unroll
      for (int i=0;i<4;++i){
        int rrow = rbase + m*16 + quad*4 + i;
        out[(size_t)NROWS*ZSD + rrow] = NC - T[m][i];
      }
  }
}

extern "C" void kernel_launch(void* const* d_in, const int* in_sizes, int n_in,
                              void* d_out, int out_size, void* d_ws, size_t ws_size,
                              hipStream_t stream)
{
  const float* mean   = (const float*)d_in[0];
  const float* logvar = (const float*)d_in[1];
  const float* eps    = (const float*)d_in[2];
  const float* W0     = (const float*)d_in[3];
  const float* b0     = (const float*)d_in[4];
  const float* W1     = (const float*)d_in[5];
  const float* b1     = (const float*)d_in[6];
  const float* W2     = (const float*)d_in[7];
  const float* b2     = (const float*)d_in[8];
  ushort_t* wgl = (ushort_t*)d_ws;          // ws_size >= 156448 proven round 3

  convert_weights<<<(WGL_SHORTS + 255)/256, 256, 0, stream>>>(W0,b0,W1,b1,W2,b2, wgl);
  flow_mfma<<<NROWS/64, 128, 0, stream>>>(mean, logvar, eps, wgl, (float*)d_out);
}